// Round 16
// baseline (100.268 us; speedup 1.0000x reference)
//
#include <hip/hip_runtime.h>
#include <hip/hip_bf16.h>
#include <stdint.h>

typedef __attribute__((ext_vector_type(4))) float f32x4;
typedef __attribute__((ext_vector_type(8))) short s16x8;

__device__ inline short f2bf(float f) {
  union { float f; uint32_t u; } v; v.f = f;
  uint32_t r = v.u + 0x7fffu + ((v.u >> 16) & 1u);  // RNE
  return (short)(r >> 16);
}

__device__ inline void gload_lds16(const void* g, void* l) {
  __builtin_amdgcn_global_load_lds((const __attribute__((address_space(1))) void*)g,
                                   (__attribute__((address_space(3))) void*)l,
                                   16, 0, 0);
}

#define MFMA16 __builtin_amdgcn_mfma_f32_16x16x32_bf16

// ---------------- Kernel 1: fused prep — X convert (blocks 0..4095) + W transpose ----
__global__ __launch_bounds__(256) void k_prep(const float* __restrict__ x,
                                              short* __restrict__ xb,
                                              const float* __restrict__ qw,
                                              const float* __restrict__ kw,
                                              const float* __restrict__ vw,
                                              short* __restrict__ wt) {
  __shared__ float tile[64][65];
  int bx = blockIdx.x;
  if (bx < 4096) {
    int i = (bx * 256 + threadIdx.x) * 8;
    const float4* p = (const float4*)(x + i);
    float4 a = p[0], b = p[1];
    s16x8 o;
    o[0] = f2bf(a.x); o[1] = f2bf(a.y); o[2] = f2bf(a.z); o[3] = f2bf(a.w);
    o[4] = f2bf(b.x); o[5] = f2bf(b.y); o[6] = f2bf(b.z); o[7] = f2bf(b.w);
    *(s16x8*)(xb + i) = o;
    return;
  }
  bx -= 4096;
  int a  = bx >> 8;
  int t2 = bx & 255;
  int k0 = (t2 >> 4) << 6;
  int n0 = (t2 & 15) << 6;
  const float* w = (a == 0) ? qw : (a == 1) ? kw : vw;
  int c = threadIdx.x & 63, rr = threadIdx.x >> 6;
#pragma unroll
  for (int i = 0; i < 16; ++i) {
    int r = i * 4 + rr;
    tile[r][c] = w[(k0 + r) * 1024 + n0 + c];
  }
  __syncthreads();
  short* o = wt + a * 1048576;
#pragma unroll
  for (int i = 0; i < 16; ++i) {
    int r = i * 4 + rr;
    o[(n0 + r) * 1024 + k0 + c] = f2bf(tile[c][r]);
  }
}

// ---------------- Kernel 2: QKV GEMM (frozen R3 triple-buffer; head-major C-write) ---
// Tile 256x128, BK=32, 4 waves (2M x 2N), per-wave 128x64 (8x4 frags).
// LDS: 3 bufs x (A 16KB + B 8KB) = 72 KB -> 2 blocks/CU. vmcnt(6) + 1 barrier / K-tile.
// Epilogue reordered (m,r outer / n inner): each head-major output row is exactly one
// 128B line; completing its four 32B segments back-to-back avoids partial-line
// eviction/rewrite (WRITE_SIZE was 70MB vs 48MB of C).
__global__ __launch_bounds__(256, 2) void k_gemm(const short* __restrict__ xb,
                                                 const short* __restrict__ wt,
                                                 const float* __restrict__ qbias,
                                                 const float* __restrict__ kbias,
                                                 const float* __restrict__ vbias,
                                                 short* __restrict__ Qo,
                                                 short* __restrict__ Ko,
                                                 short* __restrict__ Vo) {
  __shared__ short lds[36864];  // 72 KB
  const int tid = threadIdx.x, lane = tid & 63, wv = tid >> 6;
  const int wm = wv >> 1, wn = wv & 1;
  const int mt = blockIdx.x, by = blockIdx.y;
  const int a = by >> 3;
  const short* asrc = xb + (size_t)(mt * 256) * 1024;
  const short* bsrc = wt + (size_t)a * 1048576 + (size_t)((by & 7) * 128) * 1024;

  int srcA[4], dstA[4], srcB[2], dstB[2];
#pragma unroll
  for (int i = 0; i < 4; ++i) {
    int L = i * 256 + tid, s = L & 31;
    int row = (L >> 5) * 8 + (s >> 2);
    int c = (s & 3) ^ ((s >> 3) & 3);
    srcA[i] = row * 1024 + c * 8;
    dstA[i] = L * 16;
  }
#pragma unroll
  for (int i = 0; i < 2; ++i) {
    int L = i * 256 + tid, s = L & 31;
    int row = (L >> 5) * 8 + (s >> 2);
    int c = (s & 3) ^ ((s >> 3) & 3);
    srcB[i] = row * 1024 + c * 8;
    dstB[i] = 16384 + L * 16;
  }

  int aoff[8], boff[4];
#pragma unroll
  for (int m = 0; m < 8; ++m) {
    int row = wm * 128 + m * 16 + (lane & 15);
    aoff[m] = ((row >> 3) * 32 + (row & 7) * 4 + ((lane >> 4) ^ ((row >> 1) & 3))) * 16;
  }
#pragma unroll
  for (int n = 0; n < 4; ++n) {
    int row = wn * 64 + n * 16 + (lane & 15);
    boff[n] = 16384 + ((row >> 3) * 32 + (row & 7) * 4 + ((lane >> 4) ^ ((row >> 1) & 3))) * 16;
  }

  f32x4 acc[8][4] = {};

  auto STAGE = [&](int t, int bb) {
    const short* at = asrc + t * 32;
    const short* bt = bsrc + t * 32;
    char* l = (char*)lds + bb;
#pragma unroll
    for (int i = 0; i < 4; ++i) gload_lds16(at + srcA[i], l + dstA[i]);
#pragma unroll
    for (int i = 0; i < 2; ++i) gload_lds16(bt + srcB[i], l + dstB[i]);
  };

  STAGE(0, 0);
  STAGE(1, 24576);
  int bcur = 0, bpre = 49152;

  for (int t = 0; t < 31; ++t) {
    asm volatile("s_waitcnt vmcnt(6)" ::: "memory");
    __builtin_amdgcn_s_barrier();
    asm volatile("" ::: "memory");
    if (t < 30) STAGE(t + 2, bpre);
    const char* bufc = (const char*)lds + bcur;
    s16x8 af[8], bf[4];
#pragma unroll
    for (int m = 0; m < 8; ++m) af[m] = *(const s16x8*)(bufc + aoff[m]);
#pragma unroll
    for (int n = 0; n < 4; ++n) bf[n] = *(const s16x8*)(bufc + boff[n]);
    __builtin_amdgcn_s_setprio(1);
#pragma unroll
    for (int m = 0; m < 8; ++m)
#pragma unroll
      for (int n = 0; n < 4; ++n)
        acc[m][n] = MFMA16(af[m], bf[n], acc[m][n], 0, 0, 0);
    __builtin_amdgcn_s_setprio(0);
    bcur += 24576; if (bcur == 73728) bcur = 0;
    bpre += 24576; if (bpre == 73728) bpre = 0;
  }
  asm volatile("s_waitcnt vmcnt(0)" ::: "memory");
  __builtin_amdgcn_s_barrier();
  asm volatile("" ::: "memory");
  {
    const char* bufc = (const char*)lds + bcur;
    s16x8 af[8], bf[4];
#pragma unroll
    for (int m = 0; m < 8; ++m) af[m] = *(const s16x8*)(bufc + aoff[m]);
#pragma unroll
    for (int n = 0; n < 4; ++n) bf[n] = *(const s16x8*)(bufc + boff[n]);
    __builtin_amdgcn_s_setprio(1);
#pragma unroll
    for (int m = 0; m < 8; ++m)
#pragma unroll
      for (int n = 0; n < 4; ++n)
        acc[m][n] = MFMA16(af[m], bf[n], acc[m][n], 0, 0, 0);
    __builtin_amdgcn_s_setprio(0);
  }

  const float* bias = (a == 0) ? qbias : (a == 1) ? kbias : vbias;
  short* outp = (a == 0) ? Qo : (a == 1) ? Ko : Vo;
  int nbase = (by & 7) * 128 + wn * 64;   // 64-aligned -> head constant per wave
  int mbase = mt * 256 + wm * 128;
  int head = nbase >> 6;
  float bvv[4];
#pragma unroll
  for (int n = 0; n < 4; ++n) bvv[n] = bias[nbase + n * 16 + (lane & 15)];
#pragma unroll
  for (int m = 0; m < 8; ++m)
#pragma unroll
    for (int r = 0; r < 4; ++r) {
      int mm = mbase + m * 16 + ((lane >> 4) << 2) + r;
      size_t rowoff = ((size_t)head * 8192 + mm) * 64;
#pragma unroll
      for (int n = 0; n < 4; ++n) {
        int d = n * 16 + (lane & 15);
        outp[rowoff + d] = f2bf(acc[m][n][r] + bvv[n]);
      }
    }
}

// ---------------- Kernel 3: attention — flash-lite (frozen R15) ---------------------
__global__ __launch_bounds__(256, 2) void k_attn(const short* __restrict__ Qb,
                                                 const short* __restrict__ Kb,
                                                 const short* __restrict__ Vb,
                                                 const int* __restrict__ perm,
                                                 float* __restrict__ out) {
  __shared__ short Ks[128 * 64];   // 16 KB
  __shared__ short Vt[64 * 128];   // 16 KB
  __shared__ short Ps[4 * 1024];   //  8 KB

  int tid = threadIdx.x;
  int lane = tid & 63, wv = tid >> 6;
  int bx = blockIdx.x;
  int wg = (bx & 7) * 128 + (bx >> 3);
  int b = wg >> 9, g = (wg >> 5) & 15, n = (wg >> 1) & 15, h = wg & 1;
  int p = perm[g * 16 + n];
  int pg = p >> 4, ph = p & 15;

  const short* qsrc = Qb + ((size_t)n * 8192 + b * 4096 + g * 256 + h * 128) * 64;
  const short* ksrc = Kb + ((size_t)ph * 8192 + b * 4096 + pg * 256) * 64;
  const short* vsrc = Vb + ((size_t)ph * 8192 + b * 4096 + pg * 256) * 64;

  int qr0 = wv * 32;

  auto STAGE_K = [&](int hf) {
#pragma unroll
    for (int i = 0; i < 4; ++i) {
      int c = i * 256 + tid;
      int row = c >> 3;
      int sc = ((c & 7) << 4) ^ ((row & 7) << 4);
      gload_lds16(ksrc + (size_t)(hf * 128 + row) * 64 + (sc >> 1), (char*)Ks + c * 16);
    }
  };

  STAGE_K(0);
  __builtin_amdgcn_sched_barrier(0);
  s16x8 qreg[2][2];
#pragma unroll
  for (int rf = 0; rf < 2; ++rf)
#pragma unroll
    for (int ks = 0; ks < 2; ++ks) {
      int row = qr0 + rf * 16 + (lane & 15);
      qreg[rf][ks] = *(const s16x8*)(qsrc + row * 64 + ks * 32 + ((lane >> 4) << 3));
    }
  __builtin_amdgcn_sched_barrier(0);
  asm volatile("s_waitcnt vmcnt(4)" ::: "memory");
  __builtin_amdgcn_s_barrier();
  __builtin_amdgcn_sched_barrier(0);

  const float sc_log2e = 0.125f * 1.44269504088896f;
  float l_run[2][4] = {{0.f,0.f,0.f,0.f},{0.f,0.f,0.f,0.f}};
  f32x4 accO[2][4] = {};

  const int g4 = lane >> 4, s0l = (lane >> 3) & 1, kv7 = lane & 7;
  const int rs = ((lane & 1) ^ ((lane >> 3) & 1))
               | ((((lane >> 1) & 1) ^ ((lane >> 4) & 1)) << 1)
               | (((lane >> 2) & 1) << 2)
               | (((lane >> 3) & 1) << 3)
               | (((lane >> 4) & 1) << 4)
               | (((lane >> 5) & 1) << 5);

#pragma unroll
  for (int hf = 0; hf < 2; ++hf) {
    f32x4 accS[2][8];
#pragma unroll
    for (int rf = 0; rf < 2; ++rf)
#pragma unroll
      for (int cf = 0; cf < 8; ++cf) accS[rf][cf] = (f32x4){0.f, 0.f, 0.f, 0.f};
    __builtin_amdgcn_s_setprio(1);
#pragma unroll
    for (int ks = 0; ks < 2; ++ks) {
      int cb = (ks << 6) + ((lane >> 4) << 4);
#pragma unroll
      for (int cf = 0; cf < 8; ++cf) {
        int row = cf * 16 + (lane & 15);
        s16x8 bk = *(const s16x8*)((const char*)Ks + row * 128 + (cb ^ ((row & 7) << 4)));
        accS[0][cf] = MFMA16(qreg[0][ks], bk, accS[0][cf], 0, 0, 0);
        accS[1][cf] = MFMA16(qreg[1][ks], bk, accS[1][cf], 0, 0, 0);
      }
    }
    __builtin_amdgcn_s_setprio(0);

    s16x8 vreg[4];
#pragma unroll
    for (int i = 0; i < 4; ++i) {
      int c = i * 256 + tid;
      int t = c >> 3, d0 = (c & 7) << 3;
      vreg[i] = *(const s16x8*)(vsrc + (size_t)(hf * 128 + t) * 64 + d0);
    }

    __builtin_amdgcn_s_barrier();
    __builtin_amdgcn_sched_barrier(0);
    if (hf == 0) STAGE_K(1);

#pragma unroll
    for (int i = 0; i < 4; ++i) {
      int c = i * 256 + tid;
      int t = c >> 3, d0 = (c & 7) << 3;
#pragma unroll
      for (int j = 0; j < 8; ++j) {
        int d = d0 + j;
        int sl = (d & 7) ^ ((d >> 3) & 7);
        *(short*)((char*)Vt + d * 256 + ((t * 2) ^ (sl << 4))) = vreg[i][j];
      }
    }

#pragma unroll
    for (int rf = 0; rf < 2; ++rf)
#pragma unroll
      for (int cf = 0; cf < 8; ++cf)
#pragma unroll
        for (int r = 0; r < 4; ++r) {
          float e = exp2f(accS[rf][cf][r] * sc_log2e);
          accS[rf][cf][r] = e;
          l_run[rf][r] += e;
        }

    asm volatile("s_waitcnt lgkmcnt(0)" ::: "memory");
    __builtin_amdgcn_s_barrier();
    __builtin_amdgcn_sched_barrier(0);

    short* pchunk = Ps + wv * 1024;
#pragma unroll
    for (int ks = 0; ks < 4; ++ks) {
#pragma unroll
      for (int rf = 0; rf < 2; ++rf)
#pragma unroll
        for (int half = 0; half < 2; ++half) {
          int cf = ks * 2 + half;
#pragma unroll
          for (int r = 0; r < 4; ++r) {
            int slot = ((r & 1) ^ (g4 >> 1))
                     | ((((r >> 1) & 1) ^ s0l) << 1)
                     | ((g4 & 1) << 2)
                     | ((g4 >> 1) << 3)
                     | (s0l << 4)
                     | (half << 5);
            pchunk[rf * 512 + slot * 8 + kv7] = f2bf(accS[rf][cf][r]);
          }
        }
      int cbv = (ks << 6) + ((lane >> 4) << 4);
      __builtin_amdgcn_s_setprio(1);
#pragma unroll
      for (int rf = 0; rf < 2; ++rf) {
        s16x8 ap = *(const s16x8*)(pchunk + rf * 512 + rs * 8);
#pragma unroll
        for (int dc = 0; dc < 4; ++dc) {
          int vrow = dc * 16 + (lane & 15);
          int sl = (vrow & 7) ^ ((vrow >> 3) & 7);
          s16x8 bv = *(const s16x8*)((const char*)Vt + vrow * 256 + (cbv ^ (sl << 4)));
          accO[rf][dc] = MFMA16(ap, bv, accO[rf][dc], 0, 0, 0);
        }
      }
      __builtin_amdgcn_s_setprio(0);
    }

    if (hf == 0) {
      asm volatile("s_waitcnt vmcnt(0)" ::: "memory");
      __builtin_amdgcn_s_barrier();
      __builtin_amdgcn_sched_barrier(0);
    }
  }

  float inv[2][4];
#pragma unroll
  for (int rf = 0; rf < 2; ++rf)
#pragma unroll
    for (int r = 0; r < 4; ++r) {
      float s_ = l_run[rf][r];
#pragma unroll
      for (int msk = 1; msk < 16; msk <<= 1) s_ += __shfl_xor(s_, msk);
      inv[rf][r] = 1.0f / s_;
    }
#pragma unroll
  for (int rf = 0; rf < 2; ++rf)
#pragma unroll
    for (int dc = 0; dc < 4; ++dc)
#pragma unroll
      for (int r = 0; r < 4; ++r) {
        int q = h * 128 + qr0 + rf * 16 + ((lane >> 4) << 2) + r;
        int d = dc * 16 + (lane & 15);
        out[(size_t)((b * 4096 + g * 256 + q) * 16 + n) * 64 + d] = accO[rf][dc][r] * inv[rf][r];
      }
}

extern "C" void kernel_launch(void* const* d_in, const int* in_sizes, int n_in,
                              void* d_out, int out_size, void* d_ws, size_t ws_size,
                              hipStream_t stream) {
  const float* x    = (const float*)d_in[0];
  const int*   perm = (const int*)d_in[2];
  const float* qw   = (const float*)d_in[3];
  const float* qb   = (const float*)d_in[4];
  const float* kw   = (const float*)d_in[5];
  const float* kb   = (const float*)d_in[6];
  const float* vw   = (const float*)d_in[7];
  const float* vb   = (const float*)d_in[8];
  float* out = (float*)d_out;

  char* ws = (char*)d_ws;
  short* Xb = (short*)(ws);                         // 16 MB  [8192][1024] bf16
  short* Wt = (short*)(ws + 16777216UL);            //  6 MB  [3][1024 n][1024 k] bf16
  short* Qb = (short*)(ws + 23068672UL);            // 16 MB  [16][8192][64] bf16
  short* Kb = (short*)(ws + 39845888UL);            // 16 MB  [16][8192][64] bf16
  short* Vb = (short*)(ws + 56623104UL);            // 16 MB  [16][8192][64] bf16

  k_prep<<<4864, 256, 0, stream>>>(x, Xb, qw, kw, vw, Wt);
  k_gemm<<<dim3(32, 24), 256, 0, stream>>>(Xb, Wt, qb, kb, vb, Qb, Kb, Vb);
  k_attn<<<1024, 256, 0, stream>>>(Qb, Kb, Vb, perm, out);
}